// Round 8
// baseline (108.275 us; speedup 1.0000x reference)
//
#include <hip/hip_runtime.h>
#include <cstdint>

#define NTOK 16384
#define TPB 32            // tokens per block
#define YPITCH 264        // u16 pitch for Y rows (odd 16B-units: bank spread)

typedef float f4 __attribute__((ext_vector_type(4)));
typedef __attribute__((ext_vector_type(4))) float f32x4;
typedef __attribute__((ext_vector_type(8))) short bf16x8;

__device__ __forceinline__ float readlane_f(float v, int lane) {
  return __int_as_float(__builtin_amdgcn_readlane(__float_as_int(v), lane));
}

__device__ __forceinline__ float wave_sum64(float v) {
  #pragma unroll
  for (int s = 1; s < 64; s <<= 1) v += __shfl_xor(v, s, 64);
  return v;
}

__device__ __forceinline__ float half_sum32(float v) {
  #pragma unroll
  for (int s = 1; s < 32; s <<= 1) v += __shfl_xor(v, s, 64);
  return v;
}

__device__ __forceinline__ uint32_t rne_bf16(float f) {
  uint32_t u = __float_as_uint(f);
  return (u + 0x7FFFu + ((u >> 16) & 1u)) >> 16;   // round-nearest-even bf16
}

__device__ __forceinline__ float bf16f(uint32_t u) {
  return __uint_as_float(u << 16);
}

// ---------------------------------------------------------------------------
// Fused mLSTM, 2 blocks/CU. Grid 512 x 512 threads, 32 tokens/block.
// LDS = 32KB weight-half region (reused: wq|wk -> wv|wo -> Y bf16) + 17.4KB cp
//     = 49.4KB  -> TWO blocks co-resident per CU (16 waves/CU) to keep the
// HBM write queues fed (R7 showed phase-B DS work is not the limiter; the
// store stream at 8 waves/CU ran ~5.4 TB/s vs fill kernel's 6.9).
//  PhaseA: Y[32x256] = X @ [wq|wk|wv|wo] via mfma_f32_16x16x32_bf16 in two
//          half-rounds; acc stays in regs across restage; Y stored bf16.
//  PhaseB per token (4/wave):
//          n = f*n_prev + i*k
//          h = o * (f*(c_prev@q) + i*v*(k.q)) / max(|n.q|,1)
//          c = f*c_prev + i*outer(v,k) -> 16 x dwordx4, contiguous 1KB/instr
// ---------------------------------------------------------------------------
__global__ void __launch_bounds__(512, 4)
fused_kernel(const float* __restrict__ x,
             const float* __restrict__ c_prev,
             const float* __restrict__ n_prev,
             const float* __restrict__ w_q, const float* __restrict__ b_q,
             const float* __restrict__ w_k, const float* __restrict__ b_k,
             const float* __restrict__ w_v, const float* __restrict__ b_v,
             const float* __restrict__ w_i, const float* __restrict__ b_i,
             const float* __restrict__ w_f, const float* __restrict__ b_f,
             const float* __restrict__ w_o, const float* __restrict__ b_o,
             float* __restrict__ h_out,
             float* __restrict__ c_out,
             float* __restrict__ n_out)
{
  __shared__ uint32_t wbuf[8192];    // 32KB: weight half (bf16) then Y (bf16)
  __shared__ float    cp[64][68];    // 17.4KB: c_prev, padded stride
  const int tid  = threadIdx.x;
  const int lane = tid & 63;
  const int wid  = tid >> 6;
  const int T0   = blockIdx.x * TPB;

  // ---- stage half 1 (wq|wk -> n 0..127), cp, and gate x-chunks ----
  // unit(n, kb) = n*16 + (kb ^ (n&15)), kb = 16B-block along k (8 bf16)
  {
    const int n   = tid & 127;
    const int col = n & 63;
    const float* W = (n < 64) ? w_q : w_k;
    const int kph = tid >> 7;               // 0..3
    #pragma unroll
    for (int it = 0; it < 16; ++it) {
      const int kp = it * 4 + kph;          // k-pair 0..63
      const uint32_t pk = rne_bf16(W[(2 * kp) * 64 + col])
                        | (rne_bf16(W[(2 * kp + 1) * 64 + col]) << 16);
      const int unit = (n << 4) + ((kp >> 2) ^ (n & 15));
      wbuf[(unit << 2) + (kp & 3)] = pk;
    }
  }
  for (int idx = tid; idx < 4096; idx += 512)
    cp[idx >> 6][idx & 63] = c_prev[idx];

  // gate x-chunks: lane l holds x[T0+wid*4+2c+(l>>5)][4*(l&31)+e] in xc[c].e
  const f4* xp = (const f4*)(x + (size_t)(T0 + wid * 4) * 128);
  f4 xc[2];
  xc[0] = xp[lane];
  xc[1] = xp[64 + lane];

  // A-fragments (same for both MFMA rounds): m-tile mt = wid&1
  const int mt = wid & 1;
  bf16x8 afrag[4];
  {
    const float* xr = x + (size_t)(T0 + mt * 16 + (lane & 15)) * 128
                        + ((lane >> 4) * 8);
    #pragma unroll
    for (int ks = 0; ks < 4; ++ks) {
      const f4 lo = *(const f4*)(xr + ks * 32);
      const f4 hi = *(const f4*)(xr + ks * 32 + 4);
      union { uint32_t u[4]; bf16x8 v; } cv;
      cv.u[0] = rne_bf16(lo.x) | (rne_bf16(lo.y) << 16);
      cv.u[1] = rne_bf16(lo.z) | (rne_bf16(lo.w) << 16);
      cv.u[2] = rne_bf16(hi.x) | (rne_bf16(hi.y) << 16);
      cv.u[3] = rne_bf16(hi.z) | (rne_bf16(hi.w) << 16);
      afrag[ks] = cv.v;
    }
  }

  __syncthreads();

  // ---- MFMA round 1: q|k (n 0..127); wave covers 2 n-tiles ----
  const int ntg  = (wid >> 1) * 2;          // first n-tile of this wave (0..6)
  const int bsub = lane & 15, bh = lane >> 4;
  f32x4 acc_qk[2] = {(f32x4){0.f,0.f,0.f,0.f}, (f32x4){0.f,0.f,0.f,0.f}};
  #pragma unroll
  for (int nti = 0; nti < 2; ++nti) {
    const int n = (ntg + nti) * 16 + bsub;
    #pragma unroll
    for (int ks = 0; ks < 4; ++ks) {
      const int unit = (n << 4) + ((ks * 4 + bh) ^ (n & 15));
      const bf16x8 bfrag = *(const bf16x8*)&wbuf[unit << 2];
      acc_qk[nti] = __builtin_amdgcn_mfma_f32_16x16x32_bf16(afrag[ks], bfrag,
                                                            acc_qk[nti], 0, 0, 0);
    }
  }
  __syncthreads();                          // round-1 reads done

  // ---- stage half 2 (wv|wo) over the same region ----
  {
    const int n   = tid & 127;
    const int col = n & 63;
    const float* W = (n < 64) ? w_v : w_o;
    const int kph = tid >> 7;
    #pragma unroll
    for (int it = 0; it < 16; ++it) {
      const int kp = it * 4 + kph;
      const uint32_t pk = rne_bf16(W[(2 * kp) * 64 + col])
                        | (rne_bf16(W[(2 * kp + 1) * 64 + col]) << 16);
      const int unit = (n << 4) + ((kp >> 2) ^ (n & 15));
      wbuf[(unit << 2) + (kp & 3)] = pk;
    }
  }
  __syncthreads();

  // ---- MFMA round 2: v|o ----
  f32x4 acc_vo[2] = {(f32x4){0.f,0.f,0.f,0.f}, (f32x4){0.f,0.f,0.f,0.f}};
  #pragma unroll
  for (int nti = 0; nti < 2; ++nti) {
    const int n = (ntg + nti) * 16 + bsub;
    #pragma unroll
    for (int ks = 0; ks < 4; ++ks) {
      const int unit = (n << 4) + ((ks * 4 + bh) ^ (n & 15));
      const bf16x8 bfrag = *(const bf16x8*)&wbuf[unit << 2];
      acc_vo[nti] = __builtin_amdgcn_mfma_f32_16x16x32_bf16(afrag[ks], bfrag,
                                                            acc_vo[nti], 0, 0, 0);
    }
  }
  __syncthreads();                          // round-2 reads done; region dies

  // ---- write Y (bf16) into the dead weight region ----
  {
    uint16_t* y16 = (uint16_t*)wbuf;        // Y[32][YPITCH]
    const int trow = mt * 16 + (lane >> 4) * 4;
    const int fb   = ntg * 16;              // feature base within 0..127
    #pragma unroll
    for (int nti = 0; nti < 2; ++nti) {
      const int f = fb + nti * 16 + bsub;
      #pragma unroll
      for (int r = 0; r < 4; ++r) {
        y16[(trow + r) * YPITCH + f]       = (uint16_t)rne_bf16(acc_qk[nti][r]);
        y16[(trow + r) * YPITCH + 128 + f] = (uint16_t)rne_bf16(acc_vo[nti][r]);
      }
    }
  }
  __syncthreads();

  // ---- gates in full f32 (4 tokens per wave) ----
  float itv[4], ftv[4];
  {
    const int dbase = (lane & 31) << 2;
    const f4 wi4 = *(const f4*)&w_i[dbase];
    const f4 wf4 = *(const f4*)&w_f[dbase];
    const float sbi = b_i[0], sbf = b_f[0];
    #pragma unroll
    for (int c = 0; c < 2; ++c) {
      float pi = xc[c].x * wi4.x + xc[c].y * wi4.y + xc[c].z * wi4.z + xc[c].w * wi4.w;
      float pf = xc[c].x * wf4.x + xc[c].y * wf4.y + xc[c].z * wf4.z + xc[c].w * wf4.w;
      pi = half_sum32(pi);
      pf = half_sum32(pf);
      itv[2 * c]     = __expf(readlane_f(pi, 0)  + sbi);
      itv[2 * c + 1] = __expf(readlane_f(pi, 32) + sbi);
      ftv[2 * c]     = 1.0f / (1.0f + __expf(-(readlane_f(pf, 0)  + sbf)));
      ftv[2 * c + 1] = 1.0f / (1.0f + __expf(-(readlane_f(pf, 32) + sbf)));
    }
  }

  // ---- phase B: expand + store (4 tokens per wave) ----
  const float bq = b_q[lane], bk = b_k[lane], bv = b_v[lane], bo = b_o[lane];
  const float npv = n_prev[lane];
  const int   m   = lane & 15;
  const uint16_t* y16 = (const uint16_t*)wbuf;

  #pragma unroll 1
  for (int tt = 0; tt < 4; ++tt) {
    const int    tl = wid * 4 + tt;
    const size_t t  = (size_t)(T0 + tl);
    const uint16_t* yt = y16 + tl * YPITCH;
    const float q   = bf16f(yt[lane]) + bq;
    const float k   = (bf16f(yt[64 + lane]) + bk) * 0.125f;     // 1/sqrt(64)
    const float v   = bf16f(yt[128 + lane]) + bv;
    const float o   = 1.0f / (1.0f + __expf(-(bf16f(yt[192 + lane]) + bo)));
    const float it_ = itv[tt];
    const float ft_ = ftv[tt];

    const float n_val = fmaf(ft_, npv, it_ * k);
    n_out[t * 64 + lane] = n_val;

    const float nq = wave_sum64(n_val * q);
    const float kq = wave_sum64(k * q);

    // cpq[lane] = sum_j c_prev[lane][j] * q[j]
    float c0 = 0.f, c1 = 0.f, c2 = 0.f, c3 = 0.f;
    #pragma unroll
    for (int j = 0; j < 16; ++j) {
      const f4 r4 = *(const f4*)&cp[lane][4 * j];
      c0 = fmaf(r4.x, readlane_f(q, 4 * j),     c0);
      c1 = fmaf(r4.y, readlane_f(q, 4 * j + 1), c1);
      c2 = fmaf(r4.z, readlane_f(q, 4 * j + 2), c2);
      c3 = fmaf(r4.w, readlane_f(q, 4 * j + 3), c3);
    }
    const float cpq = (c0 + c1) + (c2 + c3);

    const float inv  = 1.0f / fmaxf(fabsf(nq), 1.0f);
    const float htil = fmaf(ft_, cpq, it_ * v * kq) * inv;
    h_out[t * 64 + lane] = o * htil;

    const float iv = it_ * v;
    const float k40 = __shfl(k, 4 * m, 64);
    const float k41 = __shfl(k, 4 * m + 1, 64);
    const float k42 = __shfl(k, 4 * m + 2, 64);
    const float k43 = __shfl(k, 4 * m + 3, 64);
    f4* ct = (f4*)(c_out + t * 4096);
    #pragma unroll
    for (int s = 0; s < 16; ++s) {
      const int row = 4 * s + (lane >> 4);
      const float ivr = __shfl(iv, row, 64);
      const f4 c4 = *(const f4*)&cp[row][4 * m];
      f4 val;
      val.x = fmaf(ft_, c4.x, ivr * k40);
      val.y = fmaf(ft_, c4.y, ivr * k41);
      val.z = fmaf(ft_, c4.z, ivr * k42);
      val.w = fmaf(ft_, c4.w, ivr * k43);
      ct[s * 64 + lane] = val;
    }
  }
}

extern "C" void kernel_launch(void* const* d_in, const int* in_sizes, int n_in,
                              void* d_out, int out_size, void* d_ws, size_t ws_size,
                              hipStream_t stream) {
  const float* x      = (const float*)d_in[0];
  const float* c_prev = (const float*)d_in[1];
  const float* n_prev = (const float*)d_in[2];
  const float* w_q = (const float*)d_in[3];
  const float* b_q = (const float*)d_in[4];
  const float* w_k = (const float*)d_in[5];
  const float* b_k = (const float*)d_in[6];
  const float* w_v = (const float*)d_in[7];
  const float* b_v = (const float*)d_in[8];
  const float* w_i = (const float*)d_in[9];
  const float* b_i = (const float*)d_in[10];
  const float* w_f = (const float*)d_in[11];
  const float* b_f = (const float*)d_in[12];
  const float* w_o = (const float*)d_in[13];
  const float* b_o = (const float*)d_in[14];

  float* h_out = (float*)d_out;               // 1,048,576
  float* c_out = h_out + 1048576;             // 67,108,864
  float* n_out = c_out + 67108864;            // 1,048,576

  fused_kernel<<<512, 512, 0, stream>>>(x, c_prev, n_prev,
                                        w_q, b_q, w_k, b_k, w_v, b_v,
                                        w_i, b_i, w_f, b_f, w_o, b_o,
                                        h_out, c_out, n_out);
}

// Round 9
// 56.004 us; speedup vs baseline: 1.9333x; 1.9333x over previous
//
#include <hip/hip_runtime.h>
#include <cstdint>

#define NTOK 16384

typedef float f4 __attribute__((ext_vector_type(4)));
typedef __attribute__((ext_vector_type(4))) float f32x4;
typedef __attribute__((ext_vector_type(8))) short bf16x8;

__device__ __forceinline__ float readlane_f(float v, int lane) {
  return __int_as_float(__builtin_amdgcn_readlane(__float_as_int(v), lane));
}

__device__ __forceinline__ float wave_sum64(float v) {
  #pragma unroll
  for (int s = 1; s < 64; s <<= 1) v += __shfl_xor(v, s, 64);
  return v;
}

__device__ __forceinline__ float half_sum32(float v) {
  #pragma unroll
  for (int s = 1; s < 32; s <<= 1) v += __shfl_xor(v, s, 64);
  return v;
}

__device__ __forceinline__ uint32_t rne_bf16(float f) {
  uint32_t u = __float_as_uint(f);
  return (u + 0x7FFFu + ((u >> 16) & 1u)) >> 16;   // round-nearest-even bf16
}

// ---------------------------------------------------------------------------
// Fused mLSTM, MFMA projections + register-cached c_prev store-slab.
// Grid 256 x 512 (1 block/CU, 8 waves, 64 tokens/block, 8/wave).
// R9 = R7 with the phase-B token loop unrolled 2x: interleaves token tt+1's
// y-reads / wave-reductions under token tt's 16-store burst, breaking the
// ~700-cyc serial chain that separated store bursts (all 8 waves run in
// lockstep, so those chains created CU-wide store-issue gaps).
// R8 post-mortem: 2 blocks/CU regressed 2x (VGPR cap 128 + doubled staging);
// fill kernel saturates 6.9 TB/s at 3.4 waves/CU => occupancy never limited.
// ---------------------------------------------------------------------------
__global__ void __launch_bounds__(512, 2)
fused_kernel(const float* __restrict__ x,
             const float* __restrict__ c_prev,
             const float* __restrict__ n_prev,
             const float* __restrict__ w_q, const float* __restrict__ b_q,
             const float* __restrict__ w_k, const float* __restrict__ b_k,
             const float* __restrict__ w_v, const float* __restrict__ b_v,
             const float* __restrict__ w_i, const float* __restrict__ b_i,
             const float* __restrict__ w_f, const float* __restrict__ b_f,
             const float* __restrict__ w_o, const float* __restrict__ b_o,
             float* __restrict__ h_out,
             float* __restrict__ c_out,
             float* __restrict__ n_out)
{
  __shared__ uint32_t smem[16384];   // 64KB: wT bf16 (phase A) -> Y f32 (phase B)
  __shared__ float    cp[64][68];    // 17KB: c_prev, padded stride
  const int tid  = threadIdx.x;
  const int lane = tid & 63;
  const int wid  = tid >> 6;
  const int T0   = blockIdx.x * 64;

  // ---- stage wT[n][k] as bf16 pairs, unit-swizzled ----
  // unit(n, kb) = n*16 + (kb ^ (n&15)), kb = 16B-block along k (8 bf16)
  {
    const int n   = tid & 255;
    const int col = n & 63;
    const float* W = (n < 128) ? ((n < 64) ? w_q : w_k)
                               : ((n < 192) ? w_v : w_o);
    const int kph = tid >> 8;               // 0 or 1
    #pragma unroll
    for (int it = 0; it < 32; ++it) {
      const int kp = it * 2 + kph;          // k-pair 0..63
      const float a = W[(2 * kp)     * 64 + col];
      const float b = W[(2 * kp + 1) * 64 + col];
      const uint32_t pk = rne_bf16(a) | (rne_bf16(b) << 16);
      const int unit = (n << 4) + ((kp >> 2) ^ (n & 15));
      smem[(unit << 2) + (kp & 3)] = pk;
    }
  }
  for (int idx = tid; idx < 4096; idx += 512)
    cp[idx >> 6][idx & 63] = c_prev[idx];

  // xc chunks for gates: lane l holds x[T0+wid*8+2c+(l>>5)][4*(l&31)+e]
  const f4* xp = (const f4*)(x + (size_t)(T0 + wid * 8) * 128);
  f4 xc[4];
  xc[0] = xp[lane];
  xc[1] = xp[64 + lane];
  xc[2] = xp[128 + lane];
  xc[3] = xp[192 + lane];

  __syncthreads();

  // ---- phase A: MFMA projections ----
  const int mt  = wid & 3;                  // m-tile (16 tokens)
  const int ntg = (wid >> 2) * 8;           // first of 8 n-tiles
  bf16x8 afrag[4];
  {
    const float* xr = x + (size_t)(T0 + mt * 16 + (lane & 15)) * 128
                        + ((lane >> 4) * 8);
    #pragma unroll
    for (int ks = 0; ks < 4; ++ks) {
      const f4 lo = *(const f4*)(xr + ks * 32);
      const f4 hi = *(const f4*)(xr + ks * 32 + 4);
      union { uint32_t u[4]; bf16x8 v; } cv;
      cv.u[0] = rne_bf16(lo.x) | (rne_bf16(lo.y) << 16);
      cv.u[1] = rne_bf16(lo.z) | (rne_bf16(lo.w) << 16);
      cv.u[2] = rne_bf16(hi.x) | (rne_bf16(hi.y) << 16);
      cv.u[3] = rne_bf16(hi.z) | (rne_bf16(hi.w) << 16);
      afrag[ks] = cv.v;
    }
  }
  f32x4 acc[8];
  #pragma unroll
  for (int j = 0; j < 8; ++j) acc[j] = (f32x4){0.f, 0.f, 0.f, 0.f};
  {
    const int bsub = lane & 15, bh = lane >> 4;
    #pragma unroll
    for (int nti = 0; nti < 8; ++nti) {
      const int n = (ntg + nti) * 16 + bsub;
      #pragma unroll
      for (int ks = 0; ks < 4; ++ks) {
        const int unit = (n << 4) + ((ks * 4 + bh) ^ (n & 15));
        const bf16x8 bfrag = *(const bf16x8*)&smem[unit << 2];
        acc[nti] = __builtin_amdgcn_mfma_f32_16x16x32_bf16(afrag[ks], bfrag,
                                                           acc[nti], 0, 0, 0);
      }
    }
  }
  __syncthreads();                          // all wT reads done; region dies
  {
    float* y = (float*)smem;                // Y[64][256] f32, exact 64KB
    const int trow = mt * 16 + (lane >> 4) * 4;
    const int fcol = lane & 15;
    #pragma unroll
    for (int nti = 0; nti < 8; ++nti) {
      const int f = (ntg + nti) * 16 + fcol;
      #pragma unroll
      for (int r = 0; r < 4; ++r)
        y[(trow + r) * 256 + f] = acc[nti][r];
    }
  }
  __syncthreads();

  // ---- gates in full f32 ----
  float itv[8], ftv[8];
  {
    const int dbase = (lane & 31) << 2;
    const f4 wi4 = *(const f4*)&w_i[dbase];
    const f4 wf4 = *(const f4*)&w_f[dbase];
    const float sbi = b_i[0], sbf = b_f[0];
    #pragma unroll
    for (int c = 0; c < 4; ++c) {
      float pi = xc[c].x * wi4.x + xc[c].y * wi4.y + xc[c].z * wi4.z + xc[c].w * wi4.w;
      float pf = xc[c].x * wf4.x + xc[c].y * wf4.y + xc[c].z * wf4.z + xc[c].w * wf4.w;
      pi = half_sum32(pi);
      pf = half_sum32(pf);
      itv[2 * c]     = __expf(readlane_f(pi, 0)  + sbi);
      itv[2 * c + 1] = __expf(readlane_f(pi, 32) + sbi);
      ftv[2 * c]     = 1.0f / (1.0f + __expf(-(readlane_f(pf, 0)  + sbf)));
      ftv[2 * c + 1] = 1.0f / (1.0f + __expf(-(readlane_f(pf, 32) + sbf)));
    }
  }

  // ---- register-cache the token-invariant cp store-slab ----
  // store loop needs cp[4s+(lane>>4)][4m..4m+3], s=0..15  (m = lane&15)
  const int m = lane & 15;
  f4 c4reg[16];
  #pragma unroll
  for (int s = 0; s < 16; ++s)
    c4reg[s] = *(const f4*)&cp[4 * s + (lane >> 4)][4 * m];

  // ---- phase B: expand + store (unroll 2: pipeline token pairs) ----
  const float bq = b_q[lane], bk = b_k[lane], bv = b_v[lane], bo = b_o[lane];
  const float npv = n_prev[lane];
  const float* y  = (const float*)smem;

  #pragma unroll 2
  for (int tt = 0; tt < 8; ++tt) {
    const int    tl = wid * 8 + tt;
    const size_t t  = (size_t)(T0 + tl);
    const float q   = y[tl * 256 + lane] + bq;
    const float k   = (y[tl * 256 + 64 + lane] + bk) * 0.125f;   // 1/sqrt(64)
    const float v   = y[tl * 256 + 128 + lane] + bv;
    const float o   = 1.0f / (1.0f + __expf(-(y[tl * 256 + 192 + lane] + bo)));
    const float it_ = itv[tt];
    const float ft_ = ftv[tt];

    const float n_val = fmaf(ft_, npv, it_ * k);
    n_out[t * 64 + lane] = n_val;

    const float nq = wave_sum64(n_val * q);
    const float kq = wave_sum64(k * q);

    // cpq[lane] = sum_j c_prev[lane][j] * q[j]  (row slab from LDS)
    float c0 = 0.f, c1 = 0.f, c2 = 0.f, c3 = 0.f;
    #pragma unroll
    for (int j = 0; j < 16; ++j) {
      const f4 r4 = *(const f4*)&cp[lane][4 * j];
      c0 = fmaf(r4.x, readlane_f(q, 4 * j),     c0);
      c1 = fmaf(r4.y, readlane_f(q, 4 * j + 1), c1);
      c2 = fmaf(r4.z, readlane_f(q, 4 * j + 2), c2);
      c3 = fmaf(r4.w, readlane_f(q, 4 * j + 3), c3);
    }
    const float cpq = (c0 + c1) + (c2 + c3);

    const float inv  = 1.0f / fmaxf(fabsf(nq), 1.0f);
    const float htil = fmaf(ft_, cpq, it_ * v * kq) * inv;
    h_out[t * 64 + lane] = o * htil;

    // prefetch all broadcasts, then a dense store burst
    const float iv = it_ * v;
    const float k40 = __shfl(k, 4 * m, 64);
    const float k41 = __shfl(k, 4 * m + 1, 64);
    const float k42 = __shfl(k, 4 * m + 2, 64);
    const float k43 = __shfl(k, 4 * m + 3, 64);
    float ivr[16];
    #pragma unroll
    for (int s = 0; s < 16; ++s)
      ivr[s] = __shfl(iv, 4 * s + (lane >> 4), 64);

    f4* ct = (f4*)(c_out + t * 4096);
    #pragma unroll
    for (int s = 0; s < 16; ++s) {
      f4 val;
      val.x = fmaf(ft_, c4reg[s].x, ivr[s] * k40);
      val.y = fmaf(ft_, c4reg[s].y, ivr[s] * k41);
      val.z = fmaf(ft_, c4reg[s].z, ivr[s] * k42);
      val.w = fmaf(ft_, c4reg[s].w, ivr[s] * k43);
      ct[s * 64 + lane] = val;
    }
  }
}

extern "C" void kernel_launch(void* const* d_in, const int* in_sizes, int n_in,
                              void* d_out, int out_size, void* d_ws, size_t ws_size,
                              hipStream_t stream) {
  const float* x      = (const float*)d_in[0];
  const float* c_prev = (const float*)d_in[1];
  const float* n_prev = (const float*)d_in[2];
  const float* w_q = (const float*)d_in[3];
  const float* b_q = (const float*)d_in[4];
  const float* w_k = (const float*)d_in[5];
  const float* b_k = (const float*)d_in[6];
  const float* w_v = (const float*)d_in[7];
  const float* b_v = (const float*)d_in[8];
  const float* w_i = (const float*)d_in[9];
  const float* b_i = (const float*)d_in[10];
  const float* w_f = (const float*)d_in[11];
  const float* b_f = (const float*)d_in[12];
  const float* w_o = (const float*)d_in[13];
  const float* b_o = (const float*)d_in[14];

  float* h_out = (float*)d_out;               // 1,048,576
  float* c_out = h_out + 1048576;             // 67,108,864
  float* n_out = c_out + 67108864;            // 1,048,576

  fused_kernel<<<256, 512, 0, stream>>>(x, c_prev, n_prev,
                                        w_q, b_q, w_k, b_k, w_v, b_v,
                                        w_i, b_i, w_f, b_f, w_o, b_o,
                                        h_out, c_out, n_out);
}

// Round 10
// 55.325 us; speedup vs baseline: 1.9571x; 1.0123x over previous
//
#include <hip/hip_runtime.h>
#include <cstdint>

#define NTOK 16384

typedef float f4 __attribute__((ext_vector_type(4)));
typedef __attribute__((ext_vector_type(4))) float f32x4;
typedef __attribute__((ext_vector_type(8))) short bf16x8;

__device__ __forceinline__ float readlane_f(float v, int lane) {
  return __int_as_float(__builtin_amdgcn_readlane(__float_as_int(v), lane));
}

__device__ __forceinline__ float wave_sum64(float v) {
  #pragma unroll
  for (int s = 1; s < 64; s <<= 1) v += __shfl_xor(v, s, 64);
  return v;
}

__device__ __forceinline__ float half_sum32(float v) {
  #pragma unroll
  for (int s = 1; s < 32; s <<= 1) v += __shfl_xor(v, s, 64);
  return v;
}

__device__ __forceinline__ uint32_t rne_bf16(float f) {
  uint32_t u = __float_as_uint(f);
  return (u + 0x7FFFu + ((u >> 16) & 1u)) >> 16;   // round-nearest-even bf16
}

// ---------------------------------------------------------------------------
// Fused mLSTM, MFMA projections. Grid 256 x 512 (1 block/CU, 8 waves).
// R10 targets STORE-STREAM ADDRESS QUALITY (R7/R9 proved compute-side is
// 20x under the HBM drain budget; every compute fix was neutral):
//  (1) each wave's 16-slice c-sweep is rotated by 2*wid, so the 8 lockstep
//      waves cover 8 DISTINCT 1KB offsets mod 16KB at every instant
//      (previously all 8 were congruent mod 32KB -> channel aliasing).
//  (2) h/n stores leave the c-stream: buffered in LDS in-loop, bulk-stored
//      coalesced per wave after the token loop.
// ---------------------------------------------------------------------------
__global__ void __launch_bounds__(512, 2)
fused_kernel(const float* __restrict__ x,
             const float* __restrict__ c_prev,
             const float* __restrict__ n_prev,
             const float* __restrict__ w_q, const float* __restrict__ b_q,
             const float* __restrict__ w_k, const float* __restrict__ b_k,
             const float* __restrict__ w_v, const float* __restrict__ b_v,
             const float* __restrict__ w_i, const float* __restrict__ b_i,
             const float* __restrict__ w_f, const float* __restrict__ b_f,
             const float* __restrict__ w_o, const float* __restrict__ b_o,
             float* __restrict__ h_out,
             float* __restrict__ c_out,
             float* __restrict__ n_out)
{
  __shared__ uint32_t smem[16384];   // 64KB: wT bf16 (phase A) -> Y f32 (phase B)
  __shared__ float    cp[64][68];    // 17KB: c_prev, padded stride
  __shared__ float    hbuf[4096];    // 16KB: h staging (64 tok x 64)
  __shared__ float    nbuf[4096];    // 16KB: n staging
  const int tid  = threadIdx.x;
  const int lane = tid & 63;
  const int wid  = tid >> 6;
  const int T0   = blockIdx.x * 64;

  // ---- stage wT[n][k] as bf16 pairs, unit-swizzled ----
  // unit(n, kb) = n*16 + (kb ^ (n&15)), kb = 16B-block along k (8 bf16)
  {
    const int n   = tid & 255;
    const int col = n & 63;
    const float* W = (n < 128) ? ((n < 64) ? w_q : w_k)
                               : ((n < 192) ? w_v : w_o);
    const int kph = tid >> 8;               // 0 or 1
    #pragma unroll
    for (int it = 0; it < 32; ++it) {
      const int kp = it * 2 + kph;          // k-pair 0..63
      const float a = W[(2 * kp)     * 64 + col];
      const float b = W[(2 * kp + 1) * 64 + col];
      const uint32_t pk = rne_bf16(a) | (rne_bf16(b) << 16);
      const int unit = (n << 4) + ((kp >> 2) ^ (n & 15));
      smem[(unit << 2) + (kp & 3)] = pk;
    }
  }
  for (int idx = tid; idx < 4096; idx += 512)
    cp[idx >> 6][idx & 63] = c_prev[idx];

  // xc chunks for gates: lane l holds x[T0+wid*8+2c+(l>>5)][4*(l&31)+e]
  const f4* xp = (const f4*)(x + (size_t)(T0 + wid * 8) * 128);
  f4 xc[4];
  xc[0] = xp[lane];
  xc[1] = xp[64 + lane];
  xc[2] = xp[128 + lane];
  xc[3] = xp[192 + lane];

  __syncthreads();

  // ---- phase A: MFMA projections ----
  const int mt  = wid & 3;                  // m-tile (16 tokens)
  const int ntg = (wid >> 2) * 8;           // first of 8 n-tiles
  bf16x8 afrag[4];
  {
    const float* xr = x + (size_t)(T0 + mt * 16 + (lane & 15)) * 128
                        + ((lane >> 4) * 8);
    #pragma unroll
    for (int ks = 0; ks < 4; ++ks) {
      const f4 lo = *(const f4*)(xr + ks * 32);
      const f4 hi = *(const f4*)(xr + ks * 32 + 4);
      union { uint32_t u[4]; bf16x8 v; } cv;
      cv.u[0] = rne_bf16(lo.x) | (rne_bf16(lo.y) << 16);
      cv.u[1] = rne_bf16(lo.z) | (rne_bf16(lo.w) << 16);
      cv.u[2] = rne_bf16(hi.x) | (rne_bf16(hi.y) << 16);
      cv.u[3] = rne_bf16(hi.z) | (rne_bf16(hi.w) << 16);
      afrag[ks] = cv.v;
    }
  }
  f32x4 acc[8];
  #pragma unroll
  for (int j = 0; j < 8; ++j) acc[j] = (f32x4){0.f, 0.f, 0.f, 0.f};
  {
    const int bsub = lane & 15, bh = lane >> 4;
    #pragma unroll
    for (int nti = 0; nti < 8; ++nti) {
      const int n = (ntg + nti) * 16 + bsub;
      #pragma unroll
      for (int ks = 0; ks < 4; ++ks) {
        const int unit = (n << 4) + ((ks * 4 + bh) ^ (n & 15));
        const bf16x8 bfrag = *(const bf16x8*)&smem[unit << 2];
        acc[nti] = __builtin_amdgcn_mfma_f32_16x16x32_bf16(afrag[ks], bfrag,
                                                           acc[nti], 0, 0, 0);
      }
    }
  }
  __syncthreads();                          // all wT reads done; region dies
  {
    float* y = (float*)smem;                // Y[64][256] f32, exact 64KB
    const int trow = mt * 16 + (lane >> 4) * 4;
    const int fcol = lane & 15;
    #pragma unroll
    for (int nti = 0; nti < 8; ++nti) {
      const int f = (ntg + nti) * 16 + fcol;
      #pragma unroll
      for (int r = 0; r < 4; ++r)
        y[(trow + r) * 256 + f] = acc[nti][r];
    }
  }
  __syncthreads();

  // ---- gates in full f32 ----
  float itv[8], ftv[8];
  {
    const int dbase = (lane & 31) << 2;
    const f4 wi4 = *(const f4*)&w_i[dbase];
    const f4 wf4 = *(const f4*)&w_f[dbase];
    const float sbi = b_i[0], sbf = b_f[0];
    #pragma unroll
    for (int c = 0; c < 4; ++c) {
      float pi = xc[c].x * wi4.x + xc[c].y * wi4.y + xc[c].z * wi4.z + xc[c].w * wi4.w;
      float pf = xc[c].x * wf4.x + xc[c].y * wf4.y + xc[c].z * wf4.z + xc[c].w * wf4.w;
      pi = half_sum32(pi);
      pf = half_sum32(pf);
      itv[2 * c]     = __expf(readlane_f(pi, 0)  + sbi);
      itv[2 * c + 1] = __expf(readlane_f(pi, 32) + sbi);
      ftv[2 * c]     = 1.0f / (1.0f + __expf(-(readlane_f(pf, 0)  + sbf)));
      ftv[2 * c + 1] = 1.0f / (1.0f + __expf(-(readlane_f(pf, 32) + sbf)));
    }
  }

  // ---- phase B: expand; pure c-store stream, h/n staged in LDS ----
  const float bq = b_q[lane], bk = b_k[lane], bv = b_v[lane], bo = b_o[lane];
  const float npv = n_prev[lane];
  const int   m   = lane & 15;
  const float* y  = (const float*)smem;

  #pragma unroll 1
  for (int tt = 0; tt < 8; ++tt) {
    const int    tl = wid * 8 + tt;
    const size_t t  = (size_t)(T0 + tl);
    const float q   = y[tl * 256 + lane] + bq;
    const float k   = (y[tl * 256 + 64 + lane] + bk) * 0.125f;   // 1/sqrt(64)
    const float v   = y[tl * 256 + 128 + lane] + bv;
    const float o   = 1.0f / (1.0f + __expf(-(y[tl * 256 + 192 + lane] + bo)));
    const float it_ = itv[tt];
    const float ft_ = ftv[tt];

    const float n_val = fmaf(ft_, npv, it_ * k);
    nbuf[tl * 64 + lane] = n_val;

    const float nq = wave_sum64(n_val * q);
    const float kq = wave_sum64(k * q);

    // cpq[lane] = sum_j c_prev[lane][j] * q[j]
    float c0 = 0.f, c1 = 0.f, c2 = 0.f, c3 = 0.f;
    #pragma unroll
    for (int j = 0; j < 16; ++j) {
      const f4 r4 = *(const f4*)&cp[lane][4 * j];
      c0 = fmaf(r4.x, readlane_f(q, 4 * j),     c0);
      c1 = fmaf(r4.y, readlane_f(q, 4 * j + 1), c1);
      c2 = fmaf(r4.z, readlane_f(q, 4 * j + 2), c2);
      c3 = fmaf(r4.w, readlane_f(q, 4 * j + 3), c3);
    }
    const float cpq = (c0 + c1) + (c2 + c3);

    const float inv  = 1.0f / fmaxf(fabsf(nq), 1.0f);
    const float htil = fmaf(ft_, cpq, it_ * v * kq) * inv;
    hbuf[tl * 64 + lane] = o * htil;

    // rotated c-store sweep: wave wid starts at slice 2*wid -> the 8 lockstep
    // waves write 8 distinct 1KB offsets mod 16KB at every instant
    const float iv = it_ * v;
    const float k40 = __shfl(k, 4 * m, 64);
    const float k41 = __shfl(k, 4 * m + 1, 64);
    const float k42 = __shfl(k, 4 * m + 2, 64);
    const float k43 = __shfl(k, 4 * m + 3, 64);
    f4* ct = (f4*)(c_out + t * 4096);
    #pragma unroll
    for (int s = 0; s < 16; ++s) {
      const int ss  = (s + 2 * wid) & 15;
      const int row = 4 * ss + (lane >> 4);
      const float ivr = __shfl(iv, row, 64);
      const f4 c4 = *(const f4*)&cp[row][4 * m];
      f4 val;
      val.x = fmaf(ft_, c4.x, ivr * k40);
      val.y = fmaf(ft_, c4.y, ivr * k41);
      val.z = fmaf(ft_, c4.z, ivr * k42);
      val.w = fmaf(ft_, c4.w, ivr * k43);
      ct[ss * 64 + lane] = val;
    }
  }

  // ---- bulk h/n stores: 2KB contiguous per wave, 2 x dwordx4 per lane ----
  {
    const float* hb = hbuf + wid * 512 + lane * 8;
    const float* nb = nbuf + wid * 512 + lane * 8;
    const size_t base = (size_t)(T0 + wid * 8) * 64 + lane * 8;
    f4 h0 = {hb[0], hb[1], hb[2], hb[3]};
    f4 h1 = {hb[4], hb[5], hb[6], hb[7]};
    f4 n0 = {nb[0], nb[1], nb[2], nb[3]};
    f4 n1 = {nb[4], nb[5], nb[6], nb[7]};
    *(f4*)(h_out + base)     = h0;
    *(f4*)(h_out + base + 4) = h1;
    *(f4*)(n_out + base)     = n0;
    *(f4*)(n_out + base + 4) = n1;
  }
}

extern "C" void kernel_launch(void* const* d_in, const int* in_sizes, int n_in,
                              void* d_out, int out_size, void* d_ws, size_t ws_size,
                              hipStream_t stream) {
  const float* x      = (const float*)d_in[0];
  const float* c_prev = (const float*)d_in[1];
  const float* n_prev = (const float*)d_in[2];
  const float* w_q = (const float*)d_in[3];
  const float* b_q = (const float*)d_in[4];
  const float* w_k = (const float*)d_in[5];
  const float* b_k = (const float*)d_in[6];
  const float* w_v = (const float*)d_in[7];
  const float* b_v = (const float*)d_in[8];
  const float* w_i = (const float*)d_in[9];
  const float* b_i = (const float*)d_in[10];
  const float* w_f = (const float*)d_in[11];
  const float* b_f = (const float*)d_in[12];
  const float* w_o = (const float*)d_in[13];
  const float* b_o = (const float*)d_in[14];

  float* h_out = (float*)d_out;               // 1,048,576
  float* c_out = h_out + 1048576;             // 67,108,864
  float* n_out = c_out + 67108864;            // 1,048,576

  fused_kernel<<<256, 512, 0, stream>>>(x, c_prev, n_prev,
                                        w_q, b_q, w_k, b_k, w_v, b_v,
                                        w_i, b_i, w_f, b_f, w_o, b_o,
                                        h_out, c_out, n_out);
}